// Round 4
// baseline (1133.892 us; speedup 1.0000x reference)
//
#include <hip/hip_runtime.h>

#define NN 50000
#define NE 1600000
#define GG 512
#define PAD 96
#define BN_EPS 1e-5f

__device__ __forceinline__ void fma4(float4& acc, float s, const float4& wv) {
    acc.x = fmaf(s, wv.x, acc.x);
    acc.y = fmaf(s, wv.y, acc.y);
    acc.z = fmaf(s, wv.z, acc.z);
    acc.w = fmaf(s, wv.w, acc.w);
}

// ---------------- ELL build: one pass, no hist/scan --------------------------
__global__ __launch_bounds__(256) void fill_k(const int* __restrict__ src, const int* __restrict__ dst,
                                              int* __restrict__ cnt, int* __restrict__ ell) {
    int e = blockIdx.x * 256 + threadIdx.x;
    int stp = gridDim.x * 256;
    for (; e < NE; e += stp) {
        int d = dst[e];
        int p = atomicAdd(&cnt[d], 1);
        ell[(size_t)d * PAD + p] = src[e];
    }
}

// ---------------- aggregation: m[n] = BN(h[n]) + sum_j BN(h[j]) --------------
// ss==null -> identity (layer 0). ss layout: [sc[128], sh[128]]
// BN(v) = v*sc + sh; neighbors accumulate v*sc per edge, + (1+e)*sh total.
__global__ __launch_bounds__(256) void agg_k(const int* __restrict__ cnt, const int* __restrict__ ell,
                                             const float* __restrict__ h, const float* __restrict__ ss,
                                             float* __restrict__ m) {
    int gid = blockIdx.x * 256 + threadIdx.x;
    int n = gid >> 5, l = gid & 31;
    if (n >= NN) return;
    float4 sc = {1.f, 1.f, 1.f, 1.f}, sh = {0.f, 0.f, 0.f, 0.f};
    if (ss) {
        sc = *(const float4*)(ss + l * 4);
        sh = *(const float4*)(ss + 128 + l * 4);
    }
    int e = cnt[n];
    const int* row = ell + (size_t)n * PAD;
    float4 v = *(const float4*)(h + (size_t)n * 128 + l * 4);
    float4 acc = {0.f, 0.f, 0.f, 0.f};
    fma4(acc, 1.f, make_float4(v.x * sc.x, v.y * sc.y, v.z * sc.z, v.w * sc.w));
    int i = 0;
    for (; i + 3 < e; i += 4) {
        int s0 = row[i], s1 = row[i + 1], s2 = row[i + 2], s3 = row[i + 3];
        float4 v0 = *(const float4*)(h + (size_t)s0 * 128 + l * 4);
        float4 v1 = *(const float4*)(h + (size_t)s1 * 128 + l * 4);
        float4 v2 = *(const float4*)(h + (size_t)s2 * 128 + l * 4);
        float4 v3 = *(const float4*)(h + (size_t)s3 * 128 + l * 4);
        acc.x = fmaf(v0.x, sc.x, fmaf(v1.x, sc.x, fmaf(v2.x, sc.x, fmaf(v3.x, sc.x, acc.x))));
        acc.y = fmaf(v0.y, sc.y, fmaf(v1.y, sc.y, fmaf(v2.y, sc.y, fmaf(v3.y, sc.y, acc.y))));
        acc.z = fmaf(v0.z, sc.z, fmaf(v1.z, sc.z, fmaf(v2.z, sc.z, fmaf(v3.z, sc.z, acc.z))));
        acc.w = fmaf(v0.w, sc.w, fmaf(v1.w, sc.w, fmaf(v2.w, sc.w, fmaf(v3.w, sc.w, acc.w))));
    }
    for (; i < e; ++i) {
        int s0 = row[i];
        float4 v0 = *(const float4*)(h + (size_t)s0 * 128 + l * 4);
        acc.x = fmaf(v0.x, sc.x, acc.x);
        acc.y = fmaf(v0.y, sc.y, acc.y);
        acc.z = fmaf(v0.z, sc.z, acc.z);
        acc.w = fmaf(v0.w, sc.w, acc.w);
    }
    float fe = (float)(e + 1);   // self + e neighbors each contribute sh
    acc.x = fmaf(fe, sh.x, acc.x);
    acc.y = fmaf(fe, sh.y, acc.y);
    acc.z = fmaf(fe, sh.z, acc.z);
    acc.w = fmaf(fe, sh.w, acc.w);
    *(float4*)(m + (size_t)n * 128 + l * 4) = acc;
}

// ---------------- GEMM [N,128]@[128,128] + bias + relu (+BN stats) -----------
// 64-row tile, col-split y=2 (64 cols), 4x4 register tile per thread.
__global__ __launch_bounds__(256) void mlp_gemm_k(const float* __restrict__ in, float* __restrict__ outp,
                                                  const float* __restrict__ W, const float* __restrict__ bias,
                                                  float* __restrict__ stats) {
    __shared__ float sW[128 * 64];   // 32 KB, k-major [k][c]
    __shared__ float srow[64 * 128]; // 32 KB, row-major
    const int tid = threadIdx.x;
    const int col_off = blockIdx.y * 64;
    for (int i = tid; i < 2048; i += 256) {
        int k = i >> 4, c4 = i & 15;
        *(float4*)(sW + k * 64 + c4 * 4) = *(const float4*)(W + k * 128 + col_off + c4 * 4);
    }
    const int row0 = blockIdx.x * 64;
    for (int i = tid; i < 64 * 32; i += 256) {
        int r = i >> 5, c = i & 31;
        int gr = row0 + r;
        if (gr < NN)
            *(float4*)(srow + r * 128 + c * 4) = *(const float4*)(in + (size_t)gr * 128 + c * 4);
    }
    const int tr = tid >> 4, tc = tid & 15;
    float4 bv = *(const float4*)(bias + col_off + tc * 4);
    float4 acc0 = bv, acc1 = bv, acc2 = bv, acc3 = bv;
    __syncthreads();
    const float* sr = srow + tr * 4 * 128;
    #pragma unroll 4
    for (int k = 0; k < 128; k += 4) {
        float4 a0 = *(const float4*)(sr + k);
        float4 a1 = *(const float4*)(sr + 128 + k);
        float4 a2 = *(const float4*)(sr + 256 + k);
        float4 a3 = *(const float4*)(sr + 384 + k);
        float4 w0 = *(const float4*)(sW + k * 64 + tc * 4);
        float4 w1 = *(const float4*)(sW + (k + 1) * 64 + tc * 4);
        float4 w2 = *(const float4*)(sW + (k + 2) * 64 + tc * 4);
        float4 w3 = *(const float4*)(sW + (k + 3) * 64 + tc * 4);
        fma4(acc0, a0.x, w0); fma4(acc0, a0.y, w1); fma4(acc0, a0.z, w2); fma4(acc0, a0.w, w3);
        fma4(acc1, a1.x, w0); fma4(acc1, a1.y, w1); fma4(acc1, a1.z, w2); fma4(acc1, a1.w, w3);
        fma4(acc2, a2.x, w0); fma4(acc2, a2.y, w1); fma4(acc2, a2.z, w2); fma4(acc2, a2.w, w3);
        fma4(acc3, a3.x, w0); fma4(acc3, a3.y, w1); fma4(acc3, a3.z, w2); fma4(acc3, a3.w, w3);
    }
    float4 sacc = {0.f,0.f,0.f,0.f}, qacc = {0.f,0.f,0.f,0.f};
    {
        float4 accs[4] = {acc0, acc1, acc2, acc3};
        #pragma unroll
        for (int r = 0; r < 4; ++r) {
            int gr = row0 + tr * 4 + r;
            if (gr < NN) {
                float4 a = accs[r];
                a.x = fmaxf(a.x, 0.f); a.y = fmaxf(a.y, 0.f);
                a.z = fmaxf(a.z, 0.f); a.w = fmaxf(a.w, 0.f);
                *(float4*)(outp + (size_t)gr * 128 + col_off + tc * 4) = a;
                if (stats) {
                    sacc.x += a.x; sacc.y += a.y; sacc.z += a.z; sacc.w += a.w;
                    qacc.x += a.x*a.x; qacc.y += a.y*a.y; qacc.z += a.z*a.z; qacc.w += a.w*a.w;
                }
            }
        }
    }
    if (stats) {
        __syncthreads();
        *(float4*)(srow + tr * 128 + tc * 4) = sacc;
        *(float4*)(srow + (16 + tr) * 128 + tc * 4) = qacc;
        __syncthreads();
        if (tr == 0) {
            float4 ts = {0.f,0.f,0.f,0.f}, tq = {0.f,0.f,0.f,0.f};
            for (int r = 0; r < 16; ++r) {
                float4 a = *(float4*)(srow + r * 128 + tc * 4);
                float4 b = *(float4*)(srow + (16 + r) * 128 + tc * 4);
                ts.x += a.x; ts.y += a.y; ts.z += a.z; ts.w += a.w;
                tq.x += b.x; tq.y += b.y; tq.z += b.z; tq.w += b.w;
            }
            atomicAdd(&stats[col_off + tc * 4 + 0], ts.x);
            atomicAdd(&stats[col_off + tc * 4 + 1], ts.y);
            atomicAdd(&stats[col_off + tc * 4 + 2], ts.z);
            atomicAdd(&stats[col_off + tc * 4 + 3], ts.w);
            atomicAdd(&stats[128 + col_off + tc * 4 + 0], tq.x);
            atomicAdd(&stats[128 + col_off + tc * 4 + 1], tq.y);
            atomicAdd(&stats[128 + col_off + tc * 4 + 2], tq.z);
            atomicAdd(&stats[128 + col_off + tc * 4 + 3], tq.w);
        }
    }
}

// ---------------- BN finalize: scale/shift from stats ------------------------
__global__ void bn_finalize_k(const float* __restrict__ stats, const float* __restrict__ gamma,
                              const float* __restrict__ beta, float* __restrict__ ss) {
    int d = threadIdx.x;
    float mu = stats[d] * (1.0f / NN);
    float var = stats[128 + d] * (1.0f / NN) - mu * mu;
    float sc = gamma[d] * rsqrtf(var + BN_EPS);
    ss[d] = sc;
    ss[128 + d] = beta[d] - mu * sc;
}

// ---------------- pool: per-graph sum of BN(y) (batch sorted) ----------------
__global__ __launch_bounds__(128) void pool_k(const float* __restrict__ y0, const float* __restrict__ y1,
                                              const float* __restrict__ y2, const float* __restrict__ ss,
                                              const int* __restrict__ batch, float* __restrict__ pooled) {
    int g = blockIdx.x;
    int lo = 0, hi = NN;
    while (lo < hi) { int mid = (lo + hi) >> 1; if (batch[mid] < g) lo = mid + 1; else hi = mid; }
    int s = lo;
    lo = s; hi = NN;
    while (lo < hi) { int mid = (lo + hi) >> 1; if (batch[mid] < g + 1) lo = mid + 1; else hi = mid; }
    int e = lo;
    int t = threadIdx.x;
    float sc0 = ss[t],       sh0 = ss[128 + t];
    float sc1 = ss[256 + t], sh1 = ss[384 + t];
    float sc2 = ss[512 + t], sh2 = ss[640 + t];
    float a0 = 0.f, a1 = 0.f, a2 = 0.f;
    for (int n = s; n < e; ++n) {
        a0 += fmaf(y0[(size_t)n * 128 + t], sc0, sh0);
        a1 += fmaf(y1[(size_t)n * 128 + t], sc1, sh1);
        a2 += fmaf(y2[(size_t)n * 128 + t], sc2, sh2);
    }
    pooled[(size_t)g * 384 + t] = a0;
    pooled[(size_t)g * 384 + t + 128] = a1;
    pooled[(size_t)g * 384 + t + 256] = a2;
}

// ---------------- projection head --------------------------------------------
__global__ __launch_bounds__(384) void proj_k(const float* __restrict__ pooled,
                                              const float* __restrict__ Wp1, const float* __restrict__ bp1,
                                              const float* __restrict__ Wp2, const float* __restrict__ bp2,
                                              float* __restrict__ out) {
    __shared__ float p[384];
    __shared__ float t1[384];
    int g = blockIdx.x, t = threadIdx.x;
    p[t] = pooled[(size_t)g * 384 + t];
    __syncthreads();
    float acc = bp1[t];
    #pragma unroll 4
    for (int k = 0; k < 384; ++k) acc = fmaf(p[k], Wp1[(size_t)k * 384 + t], acc);
    t1[t] = fmaxf(acc, 0.f);
    __syncthreads();
    float acc2 = bp2[t];
    #pragma unroll 4
    for (int k = 0; k < 384; ++k) acc2 = fmaf(t1[k], Wp2[(size_t)k * 384 + t], acc2);
    out[(size_t)g * 384 + t] = acc2;
}

extern "C" void kernel_launch(void* const* d_in, const int* in_sizes, int n_in,
                              void* d_out, int out_size, void* d_ws, size_t ws_size,
                              hipStream_t stream) {
    const float* x     = (const float*)d_in[0];
    const int*   ei    = (const int*)d_in[1];
    const int*   srcI  = ei;
    const int*   dstI  = ei + NE;
    const int*   batch = (const int*)d_in[2];
    const float* W1    = (const float*)d_in[3];
    const float* b1    = (const float*)d_in[4];
    const float* W2    = (const float*)d_in[5];
    const float* b2    = (const float*)d_in[6];
    const float* gamma = (const float*)d_in[7];
    const float* beta  = (const float*)d_in[8];
    const float* Wp1   = (const float*)d_in[9];
    const float* bp1   = (const float*)d_in[10];
    const float* Wp2   = (const float*)d_in[11];
    const float* bp2   = (const float*)d_in[12];
    float* out = (float*)d_out;

    float* y0     = (float*)d_ws;                    // N*128
    float* y1     = y0 + (size_t)NN * 128;           // N*128
    float* y2     = y1 + (size_t)NN * 128;           // N*128
    float* m_buf  = y2 + (size_t)NN * 128;           // N*128
    float* t_buf  = m_buf + (size_t)NN * 128;        // N*128
    float* pooled = t_buf + (size_t)NN * 128;        // G*384
    float* stats  = pooled + (size_t)GG * 384;       // 3*256
    float* ssbuf  = stats + 3 * 256;                 // 3*256
    int*   cnt    = (int*)(ssbuf + 3 * 256);         // N
    int*   ell    = cnt + NN;                        // N*PAD

    // ---- ELL build (one pass) ----
    hipMemsetAsync(cnt, 0, NN * sizeof(int), stream);
    hipMemsetAsync(stats, 0, 3 * 256 * sizeof(float), stream);
    fill_k<<<1024, 256, 0, stream>>>(srcI, dstI, cnt, ell);

    float* ybufs[3] = {y0, y1, y2};
    for (int l = 0; l < 3; ++l) {
        const float* h   = (l == 0) ? x : ybufs[l - 1];
        const float* ssl = (l == 0) ? nullptr : (ssbuf + (l - 1) * 256);

        agg_k<<<6250, 256, 0, stream>>>(cnt, ell, h, ssl, m_buf);
        {
            dim3 gg(782, 2);
            mlp_gemm_k<<<gg, 256, 0, stream>>>(m_buf, t_buf, W1 + (size_t)l * 128 * 128, b1 + l * 128, nullptr);
            mlp_gemm_k<<<gg, 256, 0, stream>>>(t_buf, ybufs[l], W2 + (size_t)l * 128 * 128, b2 + l * 128, stats + l * 256);
        }
        bn_finalize_k<<<1, 128, 0, stream>>>(stats + l * 256, gamma + l * 128, beta + l * 128, ssbuf + l * 256);
    }

    pool_k<<<GG, 128, 0, stream>>>(y0, y1, y2, ssbuf, batch, pooled);
    proj_k<<<GG, 384, 0, stream>>>(pooled, Wp1, bp1, Wp2, bp2, out);
}

// Round 5
// 881.121 us; speedup vs baseline: 1.2869x; 1.2869x over previous
//
#include <hip/hip_runtime.h>

#define NN 50000
#define NPAD 50048
#define NE 1600000
#define GG 512
#define PAD 96
#define BN_EPS 1e-5f

typedef __attribute__((ext_vector_type(8))) short short8;
typedef __attribute__((ext_vector_type(4))) float f32x4;

__device__ __forceinline__ unsigned short f2bf(float x) {
    unsigned int u = __builtin_bit_cast(unsigned int, x);
    return (unsigned short)((u + 0x7FFFu + ((u >> 16) & 1u)) >> 16);
}

// ---------------- ELL build: one pass ----------------------------------------
__global__ __launch_bounds__(256) void fill_k(const int* __restrict__ src, const int* __restrict__ dst,
                                              int* __restrict__ cnt, int* __restrict__ ell) {
    int e = blockIdx.x * 256 + threadIdx.x;
    int stp = gridDim.x * 256;
    for (; e < NE; e += stp) {
        int d = dst[e];
        int p = atomicAdd(&cnt[d], 1);
        ell[(size_t)d * PAD + p] = src[e];
    }
}

// ---------------- weight convert: W f32 [k][c] -> Wt bf16 [c][k] -------------
__global__ __launch_bounds__(256) void wconv_k(const float* __restrict__ W1, const float* __restrict__ W2,
                                               unsigned short* __restrict__ Wt) {
    int i = blockIdx.x * 256 + threadIdx.x;
    if (i >= 6 * 16384) return;
    int mat = i >> 14, rem = i & 16383;
    int c = rem >> 7, k = rem & 127;
    const float* Wsrc = (mat & 1) ? W2 : W1;
    int l = mat >> 1;
    float v = Wsrc[(size_t)l * 16384 + k * 128 + c];
    Wt[(size_t)mat * 16384 + c * 128 + k] = f2bf(v);
}

// ---------------- aggregation: m[n] = BN(h[n]) + sum_j BN(h[j]) -> bf16 ------
__global__ __launch_bounds__(256) void agg_k(const int* __restrict__ cnt, const int* __restrict__ ell,
                                             const float* __restrict__ h, const float* __restrict__ ss,
                                             unsigned short* __restrict__ m) {
    int gid = blockIdx.x * 256 + threadIdx.x;
    int n = gid >> 5, l = gid & 31;
    if (n >= NN) return;
    float4 sc = {1.f, 1.f, 1.f, 1.f}, sh = {0.f, 0.f, 0.f, 0.f};
    if (ss) {
        sc = *(const float4*)(ss + l * 4);
        sh = *(const float4*)(ss + 128 + l * 4);
    }
    int e = cnt[n];
    const int* row = ell + (size_t)n * PAD;
    float4 v = *(const float4*)(h + (size_t)n * 128 + l * 4);
    float4 acc;
    acc.x = v.x * sc.x; acc.y = v.y * sc.y; acc.z = v.z * sc.z; acc.w = v.w * sc.w;
    int i = 0;
    for (; i + 3 < e; i += 4) {
        int s0 = row[i], s1 = row[i + 1], s2 = row[i + 2], s3 = row[i + 3];
        float4 v0 = *(const float4*)(h + (size_t)s0 * 128 + l * 4);
        float4 v1 = *(const float4*)(h + (size_t)s1 * 128 + l * 4);
        float4 v2 = *(const float4*)(h + (size_t)s2 * 128 + l * 4);
        float4 v3 = *(const float4*)(h + (size_t)s3 * 128 + l * 4);
        acc.x = fmaf(v0.x, sc.x, fmaf(v1.x, sc.x, fmaf(v2.x, sc.x, fmaf(v3.x, sc.x, acc.x))));
        acc.y = fmaf(v0.y, sc.y, fmaf(v1.y, sc.y, fmaf(v2.y, sc.y, fmaf(v3.y, sc.y, acc.y))));
        acc.z = fmaf(v0.z, sc.z, fmaf(v1.z, sc.z, fmaf(v2.z, sc.z, fmaf(v3.z, sc.z, acc.z))));
        acc.w = fmaf(v0.w, sc.w, fmaf(v1.w, sc.w, fmaf(v2.w, sc.w, fmaf(v3.w, sc.w, acc.w))));
    }
    for (; i < e; ++i) {
        int s0 = row[i];
        float4 v0 = *(const float4*)(h + (size_t)s0 * 128 + l * 4);
        acc.x = fmaf(v0.x, sc.x, acc.x);
        acc.y = fmaf(v0.y, sc.y, acc.y);
        acc.z = fmaf(v0.z, sc.z, acc.z);
        acc.w = fmaf(v0.w, sc.w, acc.w);
    }
    float fe = (float)(e + 1);
    acc.x = fmaf(fe, sh.x, acc.x);
    acc.y = fmaf(fe, sh.y, acc.y);
    acc.z = fmaf(fe, sh.z, acc.z);
    acc.w = fmaf(fe, sh.w, acc.w);
    uint2 pk;
    pk.x = (unsigned int)f2bf(acc.x) | ((unsigned int)f2bf(acc.y) << 16);
    pk.y = (unsigned int)f2bf(acc.z) | ((unsigned int)f2bf(acc.w) << 16);
    *(uint2*)(m + (size_t)n * 128 + l * 4) = pk;
}

// ---------------- MFMA GEMM: [NPAD,128]bf16 @ Wt[128c][128k]bf16 -------------
// block: 256 thr / 4 waves; 64 rows x 128 cols; relu+bias fused.
// outb!=null -> bf16 out; else f32 out to outf (+ BN stats if stats!=null).
__global__ __launch_bounds__(256) void gemm_mfma_k(const unsigned short* __restrict__ A,
                                                   const unsigned short* __restrict__ Wt,
                                                   const float* __restrict__ bias,
                                                   unsigned short* __restrict__ outb,
                                                   float* __restrict__ outf,
                                                   float* __restrict__ stats) {
    __shared__ __align__(16) unsigned short sW[128 * 136];  // [col][k], pad 8
    __shared__ float sred[1024];                            // [wave][lr][c][2]
    const int tid = threadIdx.x;
    for (int ch = tid; ch < 2048; ch += 256) {
        int c = ch >> 4, i = ch & 15;
        *(uint4*)(sW + c * 136 + i * 8) = *(const uint4*)(Wt + c * 128 + i * 8);
    }
    const int w = tid >> 6, l = tid & 63;
    const int lr = l & 15, lk = l >> 4;
    const int row0 = blockIdx.x * 64 + w * 16;
    // A fragments: lane holds rows (row0+lr), k = lk*8 + s*32 .. +8
    const unsigned short* ap = A + (size_t)(row0 + lr) * 128 + lk * 8;
    short8 af0 = *(const short8*)(ap);
    short8 af1 = *(const short8*)(ap + 32);
    short8 af2 = *(const short8*)(ap + 64);
    short8 af3 = *(const short8*)(ap + 96);
    f32x4 acc[8] = {};
    __syncthreads();
    #pragma unroll
    for (int c = 0; c < 8; ++c) {
        const unsigned short* wp = sW + (c * 16 + lr) * 136 + lk * 8;
        short8 wf0 = *(const short8*)(wp);
        short8 wf1 = *(const short8*)(wp + 32);
        short8 wf2 = *(const short8*)(wp + 64);
        short8 wf3 = *(const short8*)(wp + 96);
        acc[c] = __builtin_amdgcn_mfma_f32_16x16x32_bf16(af0, wf0, acc[c], 0, 0, 0);
        acc[c] = __builtin_amdgcn_mfma_f32_16x16x32_bf16(af1, wf1, acc[c], 0, 0, 0);
        acc[c] = __builtin_amdgcn_mfma_f32_16x16x32_bf16(af2, wf2, acc[c], 0, 0, 0);
        acc[c] = __builtin_amdgcn_mfma_f32_16x16x32_bf16(af3, wf3, acc[c], 0, 0, 0);
    }
    // D: row = row0 + lk*4 + r, col = c*16 + lr
    const int drow = row0 + lk * 4;
    #pragma unroll
    for (int c = 0; c < 8; ++c) {
        int col = c * 16 + lr;
        float b = bias[col];
        float s1 = 0.f, s2 = 0.f;
        #pragma unroll
        for (int r = 0; r < 4; ++r) {
            int grow = drow + r;
            float v = fmaxf(acc[c][r] + b, 0.f);
            if (grow < NN) {
                if (outb) outb[(size_t)grow * 128 + col] = f2bf(v);
                else      outf[(size_t)grow * 128 + col] = v;
                s1 += v;
                s2 += v * v;
            }
        }
        if (stats) {
            // reduce over lk (lanes l, l^16, l^32, l^48)
            s1 += __shfl_xor(s1, 16); s1 += __shfl_xor(s1, 32);
            s2 += __shfl_xor(s2, 16); s2 += __shfl_xor(s2, 32);
            if (lk == 0) {
                sred[((w * 16 + lr) * 8 + c) * 2 + 0] = s1;
                sred[((w * 16 + lr) * 8 + c) * 2 + 1] = s2;
            }
        }
    }
    if (stats) {
        __syncthreads();
        int st = tid & 1, c = (tid >> 1) & 7, lr2 = tid >> 4;
        float t = 0.f;
        #pragma unroll
        for (int w2 = 0; w2 < 4; ++w2) t += sred[((w2 * 16 + lr2) * 8 + c) * 2 + st];
        atomicAdd(&stats[st * 128 + c * 16 + lr2], t);
    }
}

// ---------------- BN finalize ----------------
__global__ void bn_finalize_k(const float* __restrict__ stats, const float* __restrict__ gamma,
                              const float* __restrict__ beta, float* __restrict__ ss) {
    int d = threadIdx.x;
    float mu = stats[d] * (1.0f / NN);
    float var = stats[128 + d] * (1.0f / NN) - mu * mu;
    float sc = gamma[d] * rsqrtf(var + BN_EPS);
    ss[d] = sc;
    ss[128 + d] = beta[d] - mu * sc;
}

// ---------------- pool: per-graph sum of BN(y) (batch sorted) ----------------
__global__ __launch_bounds__(128) void pool_k(const float* __restrict__ y0, const float* __restrict__ y1,
                                              const float* __restrict__ y2, const float* __restrict__ ss,
                                              const int* __restrict__ batch, float* __restrict__ pooled) {
    int g = blockIdx.x;
    int lo = 0, hi = NN;
    while (lo < hi) { int mid = (lo + hi) >> 1; if (batch[mid] < g) lo = mid + 1; else hi = mid; }
    int s = lo;
    lo = s; hi = NN;
    while (lo < hi) { int mid = (lo + hi) >> 1; if (batch[mid] < g + 1) lo = mid + 1; else hi = mid; }
    int e = lo;
    int t = threadIdx.x;
    float sc0 = ss[t],       sh0 = ss[128 + t];
    float sc1 = ss[256 + t], sh1 = ss[384 + t];
    float sc2 = ss[512 + t], sh2 = ss[640 + t];
    float a0 = 0.f, a1 = 0.f, a2 = 0.f;
    for (int n = s; n < e; ++n) {
        a0 += fmaf(y0[(size_t)n * 128 + t], sc0, sh0);
        a1 += fmaf(y1[(size_t)n * 128 + t], sc1, sh1);
        a2 += fmaf(y2[(size_t)n * 128 + t], sc2, sh2);
    }
    pooled[(size_t)g * 384 + t] = a0;
    pooled[(size_t)g * 384 + t + 128] = a1;
    pooled[(size_t)g * 384 + t + 256] = a2;
}

// ---------------- projection head --------------------------------------------
__global__ __launch_bounds__(384) void proj_k(const float* __restrict__ pooled,
                                              const float* __restrict__ Wp1, const float* __restrict__ bp1,
                                              const float* __restrict__ Wp2, const float* __restrict__ bp2,
                                              float* __restrict__ out) {
    __shared__ float p[384];
    __shared__ float t1[384];
    int g = blockIdx.x, t = threadIdx.x;
    p[t] = pooled[(size_t)g * 384 + t];
    __syncthreads();
    float acc = bp1[t];
    #pragma unroll 4
    for (int k = 0; k < 384; ++k) acc = fmaf(p[k], Wp1[(size_t)k * 384 + t], acc);
    t1[t] = fmaxf(acc, 0.f);
    __syncthreads();
    float acc2 = bp2[t];
    #pragma unroll 4
    for (int k = 0; k < 384; ++k) acc2 = fmaf(t1[k], Wp2[(size_t)k * 384 + t], acc2);
    out[(size_t)g * 384 + t] = acc2;
}

extern "C" void kernel_launch(void* const* d_in, const int* in_sizes, int n_in,
                              void* d_out, int out_size, void* d_ws, size_t ws_size,
                              hipStream_t stream) {
    const float* x     = (const float*)d_in[0];
    const int*   ei    = (const int*)d_in[1];
    const int*   srcI  = ei;
    const int*   dstI  = ei + NE;
    const int*   batch = (const int*)d_in[2];
    const float* W1    = (const float*)d_in[3];
    const float* b1    = (const float*)d_in[4];
    const float* W2    = (const float*)d_in[5];
    const float* b2    = (const float*)d_in[6];
    const float* gamma = (const float*)d_in[7];
    const float* beta  = (const float*)d_in[8];
    const float* Wp1   = (const float*)d_in[9];
    const float* bp1   = (const float*)d_in[10];
    const float* Wp2   = (const float*)d_in[11];
    const float* bp2   = (const float*)d_in[12];
    float* out = (float*)d_out;

    float* y0     = (float*)d_ws;                    // N*128 f32
    float* y1     = y0 + (size_t)NN * 128;
    float* y2     = y1 + (size_t)NN * 128;
    float* pooled = y2 + (size_t)NN * 128;           // G*384
    float* stats  = pooled + (size_t)GG * 384;       // 3*256
    float* ssbuf  = stats + 3 * 256;                 // 3*256
    int*   cnt    = (int*)(ssbuf + 3 * 256);         // N
    int*   ell    = cnt + NN;                        // N*PAD
    unsigned short* m_bf = (unsigned short*)(ell + (size_t)NN * PAD); // NPAD*128 bf16
    unsigned short* t_bf = m_bf + (size_t)NPAD * 128;                 // NPAD*128 bf16
    unsigned short* Wt   = t_bf + (size_t)NPAD * 128;                 // 6*16384 bf16

    // ---- per-launch init ----
    hipMemsetAsync(cnt, 0, NN * sizeof(int), stream);
    hipMemsetAsync(stats, 0, 3 * 256 * sizeof(float), stream);
    fill_k<<<1024, 256, 0, stream>>>(srcI, dstI, cnt, ell);
    wconv_k<<<384, 256, 0, stream>>>(W1, W2, Wt);

    float* ybufs[3] = {y0, y1, y2};
    for (int l = 0; l < 3; ++l) {
        const float* h   = (l == 0) ? x : ybufs[l - 1];
        const float* ssl = (l == 0) ? nullptr : (ssbuf + (l - 1) * 256);

        agg_k<<<6250, 256, 0, stream>>>(cnt, ell, h, ssl, m_bf);
        gemm_mfma_k<<<782, 256, 0, stream>>>(m_bf, Wt + (size_t)(2 * l) * 16384, b1 + l * 128,
                                             t_bf, nullptr, nullptr);
        gemm_mfma_k<<<782, 256, 0, stream>>>(t_bf, Wt + (size_t)(2 * l + 1) * 16384, b2 + l * 128,
                                             nullptr, ybufs[l], stats + l * 256);
        bn_finalize_k<<<1, 128, 0, stream>>>(stats + l * 256, gamma + l * 128, beta + l * 128, ssbuf + l * 256);
    }

    pool_k<<<GG, 128, 0, stream>>>(y0, y1, y2, ssbuf, batch, pooled);
    proj_k<<<GG, 384, 0, stream>>>(pooled, Wp1, bp1, Wp2, bp2, out);
}

// Round 6
// 738.726 us; speedup vs baseline: 1.5349x; 1.1928x over previous
//
#include <hip/hip_runtime.h>

#define NN 50000
#define NPAD 50048
#define NE 1600000
#define GG 512
#define PAD 96
#define BN_EPS 1e-5f

typedef __attribute__((ext_vector_type(8))) short short8;
typedef __attribute__((ext_vector_type(4))) float f32x4;

__device__ __forceinline__ unsigned short f2bf(float x) {
    unsigned int u = __builtin_bit_cast(unsigned int, x);
    return (unsigned short)((u + 0x7FFFu + ((u >> 16) & 1u)) >> 16);
}
__device__ __forceinline__ float bf2f(unsigned int b) {
    return __builtin_bit_cast(float, b << 16);
}

// ---------------- ELL build (ushort ids) -------------------------------------
__global__ __launch_bounds__(256) void fill_k(const int* __restrict__ src, const int* __restrict__ dst,
                                              int* __restrict__ cnt, unsigned short* __restrict__ ell) {
    int e = blockIdx.x * 256 + threadIdx.x;
    int stp = gridDim.x * 256;
    for (; e < NE; e += stp) {
        int d = dst[e];
        int p = atomicAdd(&cnt[d], 1);
        ell[(size_t)d * PAD + p] = (unsigned short)src[e];
    }
}

// ---------------- x f32 -> bf16 ----------------------------------------------
__global__ __launch_bounds__(256) void xconv_k(const float* __restrict__ x, unsigned short* __restrict__ xb) {
    int i = blockIdx.x * 256 + threadIdx.x;
    const int tot = NN * 32;
    const int stp = gridDim.x * 256;
    for (; i < tot; i += stp) {
        float4 v = ((const float4*)x)[i];
        uint2 pk;
        pk.x = (unsigned int)f2bf(v.x) | ((unsigned int)f2bf(v.y) << 16);
        pk.y = (unsigned int)f2bf(v.z) | ((unsigned int)f2bf(v.w) << 16);
        ((uint2*)xb)[i] = pk;
    }
}

// ---------------- weight convert: W f32 [k][c] -> Wt bf16 [c][k] -------------
__global__ __launch_bounds__(256) void wconv_k(const float* __restrict__ W1, const float* __restrict__ W2,
                                               unsigned short* __restrict__ Wt) {
    int i = blockIdx.x * 256 + threadIdx.x;
    if (i >= 6 * 16384) return;
    int mat = i >> 14, rem = i & 16383;
    int c = rem >> 7, k = rem & 127;
    const float* Wsrc = (mat & 1) ? W2 : W1;
    int l = mat >> 1;
    float v = Wsrc[(size_t)l * 16384 + k * 128 + c];
    Wt[(size_t)mat * 16384 + c * 128 + k] = f2bf(v);
}

// ---------------- aggregation: m[n] = BN(h[n]) + sum_j BN(h[j]), bf16 in/out -
// 16 lanes per node; lane handles 8 cols.
__global__ __launch_bounds__(256) void agg_k(const int* __restrict__ cnt, const unsigned short* __restrict__ ell,
                                             const unsigned short* __restrict__ h, const float* __restrict__ ss,
                                             unsigned short* __restrict__ m) {
    int gid = blockIdx.x * 256 + threadIdx.x;
    int n = gid >> 4, l = gid & 15;
    if (n >= NN) return;
    float sc[8], sh[8];
    #pragma unroll
    for (int j = 0; j < 8; ++j) { sc[j] = 1.f; sh[j] = 0.f; }
    if (ss) {
        #pragma unroll
        for (int j = 0; j < 8; ++j) { sc[j] = ss[l * 8 + j]; sh[j] = ss[128 + l * 8 + j]; }
    }
    int e = cnt[n];
    const unsigned short* row = ell + (size_t)n * PAD;
    float acc[8];
    {
        uint4 q = *(const uint4*)(h + (size_t)n * 128 + l * 8);
        unsigned int qq[4] = {q.x, q.y, q.z, q.w};
        #pragma unroll
        for (int j = 0; j < 4; ++j) {
            acc[2 * j]     = bf2f(qq[j] & 0xffffu) * sc[2 * j];
            acc[2 * j + 1] = bf2f(qq[j] >> 16)     * sc[2 * j + 1];
        }
    }
    int i = 0;
    for (; i + 4 <= e; i += 4) {
        uint2 ip = *(const uint2*)(row + i);
        int s0 = ip.x & 0xffff, s1 = ip.x >> 16, s2 = ip.y & 0xffff, s3 = ip.y >> 16;
        uint4 q0 = *(const uint4*)(h + (size_t)s0 * 128 + l * 8);
        uint4 q1 = *(const uint4*)(h + (size_t)s1 * 128 + l * 8);
        uint4 q2 = *(const uint4*)(h + (size_t)s2 * 128 + l * 8);
        uint4 q3 = *(const uint4*)(h + (size_t)s3 * 128 + l * 8);
        unsigned int a0[4] = {q0.x, q0.y, q0.z, q0.w};
        unsigned int a1[4] = {q1.x, q1.y, q1.z, q1.w};
        unsigned int a2[4] = {q2.x, q2.y, q2.z, q2.w};
        unsigned int a3[4] = {q3.x, q3.y, q3.z, q3.w};
        #pragma unroll
        for (int j = 0; j < 4; ++j) {
            acc[2*j]   = fmaf(bf2f(a0[j] & 0xffffu), sc[2*j],
                         fmaf(bf2f(a1[j] & 0xffffu), sc[2*j],
                         fmaf(bf2f(a2[j] & 0xffffu), sc[2*j],
                         fmaf(bf2f(a3[j] & 0xffffu), sc[2*j], acc[2*j]))));
            acc[2*j+1] = fmaf(bf2f(a0[j] >> 16), sc[2*j+1],
                         fmaf(bf2f(a1[j] >> 16), sc[2*j+1],
                         fmaf(bf2f(a2[j] >> 16), sc[2*j+1],
                         fmaf(bf2f(a3[j] >> 16), sc[2*j+1], acc[2*j+1]))));
        }
    }
    for (; i < e; ++i) {
        int s0 = row[i];
        uint4 q = *(const uint4*)(h + (size_t)s0 * 128 + l * 8);
        unsigned int qq[4] = {q.x, q.y, q.z, q.w};
        #pragma unroll
        for (int j = 0; j < 4; ++j) {
            acc[2*j]   = fmaf(bf2f(qq[j] & 0xffffu), sc[2*j],   acc[2*j]);
            acc[2*j+1] = fmaf(bf2f(qq[j] >> 16),     sc[2*j+1], acc[2*j+1]);
        }
    }
    float fe = (float)(e + 1);
    #pragma unroll
    for (int j = 0; j < 8; ++j) acc[j] = fmaf(fe, sh[j], acc[j]);
    uint4 pk;
    pk.x = (unsigned int)f2bf(acc[0]) | ((unsigned int)f2bf(acc[1]) << 16);
    pk.y = (unsigned int)f2bf(acc[2]) | ((unsigned int)f2bf(acc[3]) << 16);
    pk.z = (unsigned int)f2bf(acc[4]) | ((unsigned int)f2bf(acc[5]) << 16);
    pk.w = (unsigned int)f2bf(acc[6]) | ((unsigned int)f2bf(acc[7]) << 16);
    *(uint4*)(m + (size_t)n * 128 + l * 8) = pk;
}

// ---------------- fused MLP: y = relu(relu(m@W1+b1)@W2+b2), bf16 out + stats -
// 256 thr / 4 waves; 64 rows x 128 cols per block; W1 then W2 staged in sW.
__global__ __launch_bounds__(256) void mlp_k(const unsigned short* __restrict__ A,
                                             const unsigned short* __restrict__ Wt,
                                             const float* __restrict__ bias1,
                                             const float* __restrict__ bias2,
                                             unsigned short* __restrict__ yb,
                                             float* __restrict__ stats) {
    __shared__ __align__(16) unsigned short sW[128 * 136];  // 34 KB
    __shared__ __align__(16) unsigned short sT[64 * 136];   // 17 KB
    __shared__ float sred[1024];                            // 4 KB
    const int tid = threadIdx.x;
    for (int ch = tid; ch < 2048; ch += 256) {
        int c = ch >> 4, i = ch & 15;
        *(uint4*)(sW + c * 136 + i * 8) = *(const uint4*)(Wt + c * 128 + i * 8);
    }
    const int w = tid >> 6, l = tid & 63;
    const int lr = l & 15, lk = l >> 4;
    const int row0 = blockIdx.x * 64 + w * 16;
    const unsigned short* ap = A + (size_t)(row0 + lr) * 128 + lk * 8;
    short8 af0 = *(const short8*)(ap);
    short8 af1 = *(const short8*)(ap + 32);
    short8 af2 = *(const short8*)(ap + 64);
    short8 af3 = *(const short8*)(ap + 96);
    f32x4 acc[8] = {};
    __syncthreads();
    #pragma unroll
    for (int c = 0; c < 8; ++c) {
        const unsigned short* wp = sW + (c * 16 + lr) * 136 + lk * 8;
        short8 wf0 = *(const short8*)(wp);
        short8 wf1 = *(const short8*)(wp + 32);
        short8 wf2 = *(const short8*)(wp + 64);
        short8 wf3 = *(const short8*)(wp + 96);
        acc[c] = __builtin_amdgcn_mfma_f32_16x16x32_bf16(af0, wf0, acc[c], 0, 0, 0);
        acc[c] = __builtin_amdgcn_mfma_f32_16x16x32_bf16(af1, wf1, acc[c], 0, 0, 0);
        acc[c] = __builtin_amdgcn_mfma_f32_16x16x32_bf16(af2, wf2, acc[c], 0, 0, 0);
        acc[c] = __builtin_amdgcn_mfma_f32_16x16x32_bf16(af3, wf3, acc[c], 0, 0, 0);
    }
    // epilogue 1: bias1+relu -> sT (local row = w*16 + lk*4 + r, col = c*16+lr)
    const int lrow = w * 16 + lk * 4;
    #pragma unroll
    for (int c = 0; c < 8; ++c) {
        int col = c * 16 + lr;
        float b = bias1[col];
        #pragma unroll
        for (int r = 0; r < 4; ++r) {
            float v = fmaxf(acc[c][r] + b, 0.f);
            sT[(lrow + r) * 136 + col] = f2bf(v);
        }
    }
    __syncthreads();   // sT complete; all W1 reads done -> safe to overwrite sW
    for (int ch = tid; ch < 2048; ch += 256) {
        int c = ch >> 4, i = ch & 15;
        *(uint4*)(sW + c * 136 + i * 8) = *(const uint4*)(Wt + 16384 + c * 128 + i * 8);
    }
    const unsigned short* tp = sT + (w * 16 + lr) * 136 + lk * 8;
    short8 bf0 = *(const short8*)(tp);
    short8 bf1 = *(const short8*)(tp + 32);
    short8 bf2_ = *(const short8*)(tp + 64);
    short8 bf3 = *(const short8*)(tp + 96);
    f32x4 acc2[8] = {};
    __syncthreads();
    #pragma unroll
    for (int c = 0; c < 8; ++c) {
        const unsigned short* wp = sW + (c * 16 + lr) * 136 + lk * 8;
        short8 wf0 = *(const short8*)(wp);
        short8 wf1 = *(const short8*)(wp + 32);
        short8 wf2 = *(const short8*)(wp + 64);
        short8 wf3 = *(const short8*)(wp + 96);
        acc2[c] = __builtin_amdgcn_mfma_f32_16x16x32_bf16(bf0, wf0, acc2[c], 0, 0, 0);
        acc2[c] = __builtin_amdgcn_mfma_f32_16x16x32_bf16(bf1, wf1, acc2[c], 0, 0, 0);
        acc2[c] = __builtin_amdgcn_mfma_f32_16x16x32_bf16(bf2_, wf2, acc2[c], 0, 0, 0);
        acc2[c] = __builtin_amdgcn_mfma_f32_16x16x32_bf16(bf3, wf3, acc2[c], 0, 0, 0);
    }
    const int drow = row0 + lk * 4;
    #pragma unroll
    for (int c = 0; c < 8; ++c) {
        int col = c * 16 + lr;
        float b = bias2[col];
        float s1 = 0.f, s2 = 0.f;
        #pragma unroll
        for (int r = 0; r < 4; ++r) {
            int grow = drow + r;
            float v = fmaxf(acc2[c][r] + b, 0.f);
            if (grow < NN) {
                yb[(size_t)grow * 128 + col] = f2bf(v);
                s1 += v;
                s2 += v * v;
            }
        }
        s1 += __shfl_xor(s1, 16); s1 += __shfl_xor(s1, 32);
        s2 += __shfl_xor(s2, 16); s2 += __shfl_xor(s2, 32);
        if (lk == 0) {
            sred[((w * 16 + lr) * 8 + c) * 2 + 0] = s1;
            sred[((w * 16 + lr) * 8 + c) * 2 + 1] = s2;
        }
    }
    __syncthreads();
    int st = tid & 1, c = (tid >> 1) & 7, lr2 = tid >> 4;
    float t = 0.f;
    #pragma unroll
    for (int w2 = 0; w2 < 4; ++w2) t += sred[((w2 * 16 + lr2) * 8 + c) * 2 + st];
    atomicAdd(&stats[st * 128 + c * 16 + lr2], t);
}

// ---------------- BN finalize ----------------
__global__ void bn_finalize_k(const float* __restrict__ stats, const float* __restrict__ gamma,
                              const float* __restrict__ beta, float* __restrict__ ss) {
    int d = threadIdx.x;
    float mu = stats[d] * (1.0f / NN);
    float var = stats[128 + d] * (1.0f / NN) - mu * mu;
    float sc = gamma[d] * rsqrtf(var + BN_EPS);
    ss[d] = sc;
    ss[128 + d] = beta[d] - mu * sc;
}

// ---------------- pool: per-graph sum of BN(y bf16) (batch sorted) -----------
__global__ __launch_bounds__(128) void pool_k(const unsigned short* __restrict__ y0,
                                              const unsigned short* __restrict__ y1,
                                              const unsigned short* __restrict__ y2,
                                              const float* __restrict__ ss,
                                              const int* __restrict__ batch, float* __restrict__ pooled) {
    int g = blockIdx.x;
    int lo = 0, hi = NN;
    while (lo < hi) { int mid = (lo + hi) >> 1; if (batch[mid] < g) lo = mid + 1; else hi = mid; }
    int s = lo;
    lo = s; hi = NN;
    while (lo < hi) { int mid = (lo + hi) >> 1; if (batch[mid] < g + 1) lo = mid + 1; else hi = mid; }
    int e = lo;
    int t = threadIdx.x;
    float sc0 = ss[t],       sh0 = ss[128 + t];
    float sc1 = ss[256 + t], sh1 = ss[384 + t];
    float sc2 = ss[512 + t], sh2 = ss[640 + t];
    float a0 = 0.f, a1 = 0.f, a2 = 0.f;
    for (int n = s; n < e; ++n) {
        a0 += fmaf(bf2f((unsigned int)y0[(size_t)n * 128 + t]), sc0, sh0);
        a1 += fmaf(bf2f((unsigned int)y1[(size_t)n * 128 + t]), sc1, sh1);
        a2 += fmaf(bf2f((unsigned int)y2[(size_t)n * 128 + t]), sc2, sh2);
    }
    pooled[(size_t)g * 384 + t] = a0;
    pooled[(size_t)g * 384 + t + 128] = a1;
    pooled[(size_t)g * 384 + t + 256] = a2;
}

// ---------------- projection head --------------------------------------------
__global__ __launch_bounds__(384) void proj_k(const float* __restrict__ pooled,
                                              const float* __restrict__ Wp1, const float* __restrict__ bp1,
                                              const float* __restrict__ Wp2, const float* __restrict__ bp2,
                                              float* __restrict__ out) {
    __shared__ float p[384];
    __shared__ float t1[384];
    int g = blockIdx.x, t = threadIdx.x;
    p[t] = pooled[(size_t)g * 384 + t];
    __syncthreads();
    float acc = bp1[t];
    #pragma unroll 4
    for (int k = 0; k < 384; ++k) acc = fmaf(p[k], Wp1[(size_t)k * 384 + t], acc);
    t1[t] = fmaxf(acc, 0.f);
    __syncthreads();
    float acc2 = bp2[t];
    #pragma unroll 4
    for (int k = 0; k < 384; ++k) acc2 = fmaf(t1[k], Wp2[(size_t)k * 384 + t], acc2);
    out[(size_t)g * 384 + t] = acc2;
}

extern "C" void kernel_launch(void* const* d_in, const int* in_sizes, int n_in,
                              void* d_out, int out_size, void* d_ws, size_t ws_size,
                              hipStream_t stream) {
    const float* x     = (const float*)d_in[0];
    const int*   ei    = (const int*)d_in[1];
    const int*   srcI  = ei;
    const int*   dstI  = ei + NE;
    const int*   batch = (const int*)d_in[2];
    const float* W1    = (const float*)d_in[3];
    const float* b1    = (const float*)d_in[4];
    const float* W2    = (const float*)d_in[5];
    const float* b2    = (const float*)d_in[6];
    const float* gamma = (const float*)d_in[7];
    const float* beta  = (const float*)d_in[8];
    const float* Wp1   = (const float*)d_in[9];
    const float* bp1   = (const float*)d_in[10];
    const float* Wp2   = (const float*)d_in[11];
    const float* bp2   = (const float*)d_in[12];
    float* out = (float*)d_out;

    float* pooled = (float*)d_ws;                     // G*384
    float* stats  = pooled + (size_t)GG * 384;        // 3*256
    float* ssbuf  = stats + 3 * 256;                  // 3*256
    int*   cnt    = (int*)(ssbuf + 3 * 256);          // N
    unsigned short* ell  = (unsigned short*)(cnt + NN);        // N*PAD
    unsigned short* xb   = ell + (size_t)NN * PAD;             // N*128
    unsigned short* yb0  = xb + (size_t)NN * 128;
    unsigned short* yb1  = yb0 + (size_t)NN * 128;
    unsigned short* yb2  = yb1 + (size_t)NN * 128;
    unsigned short* m_bf = yb2 + (size_t)NN * 128;             // NPAD*128
    unsigned short* Wt   = m_bf + (size_t)NPAD * 128;          // 6*16384

    hipMemsetAsync(cnt, 0, NN * sizeof(int), stream);
    hipMemsetAsync(stats, 0, 3 * 256 * sizeof(float), stream);
    fill_k<<<2048, 256, 0, stream>>>(srcI, dstI, cnt, ell);
    xconv_k<<<1024, 256, 0, stream>>>(x, xb);
    wconv_k<<<384, 256, 0, stream>>>(W1, W2, Wt);

    unsigned short* ybufs[3] = {yb0, yb1, yb2};
    for (int l = 0; l < 3; ++l) {
        const unsigned short* h = (l == 0) ? xb : ybufs[l - 1];
        const float* ssl        = (l == 0) ? nullptr : (ssbuf + (l - 1) * 256);

        agg_k<<<3125, 256, 0, stream>>>(cnt, ell, h, ssl, m_bf);
        mlp_k<<<782, 256, 0, stream>>>(m_bf, Wt + (size_t)(2 * l) * 16384,
                                       b1 + l * 128, b2 + l * 128,
                                       ybufs[l], stats + l * 256);
        bn_finalize_k<<<1, 128, 0, stream>>>(stats + l * 256, gamma + l * 128, beta + l * 128, ssbuf + l * 256);
    }

    pool_k<<<GG, 128, 0, stream>>>(yb0, yb1, yb2, ssbuf, batch, pooled);
    proj_k<<<GG, 384, 0, stream>>>(pooled, Wp1, bp1, Wp2, bp2, out);
}

// Round 7
// 637.961 us; speedup vs baseline: 1.7774x; 1.1579x over previous
//
#include <hip/hip_runtime.h>

#define NN 50000
#define NPAD 50048
#define NE 1600000
#define GG 512
#define PAD 96
#define NBKT 196
#define BCAP 12288
#define CHUNK 6250
#define BN_EPS 1e-5f

typedef __attribute__((ext_vector_type(8))) short short8;
typedef __attribute__((ext_vector_type(4))) float f32x4;

__device__ __forceinline__ unsigned short f2bf(float x) {
    unsigned int u = __builtin_bit_cast(unsigned int, x);
    return (unsigned short)((u + 0x7FFFu + ((u >> 16) & 1u)) >> 16);
}
__device__ __forceinline__ float bf2f(unsigned int b) {
    return __builtin_bit_cast(float, b << 16);
}

// ---------------- phase 1: bucket edges by dst>>8 into staging ---------------
__global__ __launch_bounds__(256) void bucket_k(const int* __restrict__ src, const int* __restrict__ dst,
                                                int* __restrict__ bcur, unsigned int* __restrict__ staging) {
    __shared__ int hist[NBKT];
    __shared__ int curs[NBKT];
    const int t = threadIdx.x;
    if (t < NBKT) hist[t] = 0;
    __syncthreads();
    const int e0 = blockIdx.x * CHUNK;
    const int e1 = e0 + CHUNK;
    for (int e = e0 + t; e < e1; e += 256) atomicAdd(&hist[dst[e] >> 8], 1);
    __syncthreads();
    if (t < NBKT) {
        int c = hist[t];
        curs[t] = (c > 0) ? atomicAdd(&bcur[t], c) : 0;
    }
    __syncthreads();
    for (int e = e0 + t; e < e1; e += 256) {
        int d = dst[e];
        int b = d >> 8;
        int pos = atomicAdd(&curs[b], 1);
        staging[(size_t)b * BCAP + pos] = (unsigned int)(d & 255) | ((unsigned int)src[e] << 8);
    }
}

// ---------------- phase 2: bucket -> LDS ELL tile -> coalesced global --------
__global__ __launch_bounds__(256) void ellfill_k(const int* __restrict__ bcur,
                                                 const unsigned int* __restrict__ staging,
                                                 int* __restrict__ cnt, unsigned short* __restrict__ ell) {
    __shared__ unsigned short lell[256 * PAD]; // 48 KB
    __shared__ int lcnt[256];
    const int b = blockIdx.x, t = threadIdx.x;
    lcnt[t] = 0;
    __syncthreads();
    const int tot = bcur[b];
    const unsigned int* sg = staging + (size_t)b * BCAP;
    for (int i = t; i < tot; i += 256) {
        unsigned int v = sg[i];
        int r = v & 255;
        int p = atomicAdd(&lcnt[r], 1);
        lell[r * PAD + p] = (unsigned short)(v >> 8);
    }
    __syncthreads();
    const int n0 = b << 8;
    const int nrows = min(256, NN - n0);
    for (int i = t; i < nrows * 12; i += 256) {
        int r = i / 12, q = i % 12;
        *(uint4*)(ell + (size_t)(n0 + r) * PAD + q * 8) = *(const uint4*)(lell + r * PAD + q * 8);
    }
    if (t < nrows) cnt[n0 + t] = lcnt[t];
}

// ---------------- x f32 -> bf16 ----------------------------------------------
__global__ __launch_bounds__(256) void xconv_k(const float* __restrict__ x, unsigned short* __restrict__ xb) {
    int i = blockIdx.x * 256 + threadIdx.x;
    const int tot = NN * 32;
    const int stp = gridDim.x * 256;
    for (; i < tot; i += stp) {
        float4 v = ((const float4*)x)[i];
        uint2 pk;
        pk.x = (unsigned int)f2bf(v.x) | ((unsigned int)f2bf(v.y) << 16);
        pk.y = (unsigned int)f2bf(v.z) | ((unsigned int)f2bf(v.w) << 16);
        ((uint2*)xb)[i] = pk;
    }
}

// ---------------- weight convert: W f32 [k][c] -> Wt bf16 [c][k] -------------
__global__ __launch_bounds__(256) void wconv_k(const float* __restrict__ W1, const float* __restrict__ W2,
                                               unsigned short* __restrict__ Wt) {
    int i = blockIdx.x * 256 + threadIdx.x;
    if (i >= 6 * 16384) return;
    int mat = i >> 14, rem = i & 16383;
    int c = rem >> 7, k = rem & 127;
    const float* Wsrc = (mat & 1) ? W2 : W1;
    int l = mat >> 1;
    float v = Wsrc[(size_t)l * 16384 + k * 128 + c];
    Wt[(size_t)mat * 16384 + c * 128 + k] = f2bf(v);
}

// ---------------- aggregation: m[n] = BN(h[n]) + sum_j BN(h[j]), bf16 --------
__global__ __launch_bounds__(256) void agg_k(const int* __restrict__ cnt, const unsigned short* __restrict__ ell,
                                             const unsigned short* __restrict__ h, const float* __restrict__ ss,
                                             unsigned short* __restrict__ m) {
    int gid = blockIdx.x * 256 + threadIdx.x;
    int n = gid >> 4, l = gid & 15;
    if (n >= NN) return;
    float sc[8], sh[8];
    #pragma unroll
    for (int j = 0; j < 8; ++j) { sc[j] = 1.f; sh[j] = 0.f; }
    if (ss) {
        #pragma unroll
        for (int j = 0; j < 8; ++j) { sc[j] = ss[l * 8 + j]; sh[j] = ss[128 + l * 8 + j]; }
    }
    int e = cnt[n];
    const unsigned short* row = ell + (size_t)n * PAD;
    float acc[8];
    {
        uint4 q = *(const uint4*)(h + (size_t)n * 128 + l * 8);
        unsigned int qq[4] = {q.x, q.y, q.z, q.w};
        #pragma unroll
        for (int j = 0; j < 4; ++j) {
            acc[2 * j]     = bf2f(qq[j] & 0xffffu) * sc[2 * j];
            acc[2 * j + 1] = bf2f(qq[j] >> 16)     * sc[2 * j + 1];
        }
    }
    int i = 0;
    for (; i + 4 <= e; i += 4) {
        uint2 ip = *(const uint2*)(row + i);
        int s0 = ip.x & 0xffff, s1 = ip.x >> 16, s2 = ip.y & 0xffff, s3 = ip.y >> 16;
        uint4 q0 = *(const uint4*)(h + (size_t)s0 * 128 + l * 8);
        uint4 q1 = *(const uint4*)(h + (size_t)s1 * 128 + l * 8);
        uint4 q2 = *(const uint4*)(h + (size_t)s2 * 128 + l * 8);
        uint4 q3 = *(const uint4*)(h + (size_t)s3 * 128 + l * 8);
        unsigned int a0[4] = {q0.x, q0.y, q0.z, q0.w};
        unsigned int a1[4] = {q1.x, q1.y, q1.z, q1.w};
        unsigned int a2[4] = {q2.x, q2.y, q2.z, q2.w};
        unsigned int a3[4] = {q3.x, q3.y, q3.z, q3.w};
        #pragma unroll
        for (int j = 0; j < 4; ++j) {
            acc[2*j]   = fmaf(bf2f(a0[j] & 0xffffu), sc[2*j],
                         fmaf(bf2f(a1[j] & 0xffffu), sc[2*j],
                         fmaf(bf2f(a2[j] & 0xffffu), sc[2*j],
                         fmaf(bf2f(a3[j] & 0xffffu), sc[2*j], acc[2*j]))));
            acc[2*j+1] = fmaf(bf2f(a0[j] >> 16), sc[2*j+1],
                         fmaf(bf2f(a1[j] >> 16), sc[2*j+1],
                         fmaf(bf2f(a2[j] >> 16), sc[2*j+1],
                         fmaf(bf2f(a3[j] >> 16), sc[2*j+1], acc[2*j+1]))));
        }
    }
    for (; i < e; ++i) {
        int s0 = row[i];
        uint4 q = *(const uint4*)(h + (size_t)s0 * 128 + l * 8);
        unsigned int qq[4] = {q.x, q.y, q.z, q.w};
        #pragma unroll
        for (int j = 0; j < 4; ++j) {
            acc[2*j]   = fmaf(bf2f(qq[j] & 0xffffu), sc[2*j],   acc[2*j]);
            acc[2*j+1] = fmaf(bf2f(qq[j] >> 16),     sc[2*j+1], acc[2*j+1]);
        }
    }
    float fe = (float)(e + 1);
    #pragma unroll
    for (int j = 0; j < 8; ++j) acc[j] = fmaf(fe, sh[j], acc[j]);
    uint4 pk;
    pk.x = (unsigned int)f2bf(acc[0]) | ((unsigned int)f2bf(acc[1]) << 16);
    pk.y = (unsigned int)f2bf(acc[2]) | ((unsigned int)f2bf(acc[3]) << 16);
    pk.z = (unsigned int)f2bf(acc[4]) | ((unsigned int)f2bf(acc[5]) << 16);
    pk.w = (unsigned int)f2bf(acc[6]) | ((unsigned int)f2bf(acc[7]) << 16);
    *(uint4*)(m + (size_t)n * 128 + l * 8) = pk;
}

// ---------------- fused MLP: y = relu(relu(m@W1+b1)@W2+b2), bf16 out + stats -
__global__ __launch_bounds__(256) void mlp_k(const unsigned short* __restrict__ A,
                                             const unsigned short* __restrict__ Wt,
                                             const float* __restrict__ bias1,
                                             const float* __restrict__ bias2,
                                             unsigned short* __restrict__ yb,
                                             float* __restrict__ stats) {
    __shared__ __align__(16) unsigned short sW[128 * 136];
    __shared__ __align__(16) unsigned short sT[64 * 136];
    __shared__ float sred[1024];
    const int tid = threadIdx.x;
    for (int ch = tid; ch < 2048; ch += 256) {
        int c = ch >> 4, i = ch & 15;
        *(uint4*)(sW + c * 136 + i * 8) = *(const uint4*)(Wt + c * 128 + i * 8);
    }
    const int w = tid >> 6, l = tid & 63;
    const int lr = l & 15, lk = l >> 4;
    const int row0 = blockIdx.x * 64 + w * 16;
    const unsigned short* ap = A + (size_t)(row0 + lr) * 128 + lk * 8;
    short8 af0 = *(const short8*)(ap);
    short8 af1 = *(const short8*)(ap + 32);
    short8 af2 = *(const short8*)(ap + 64);
    short8 af3 = *(const short8*)(ap + 96);
    f32x4 acc[8] = {};
    __syncthreads();
    #pragma unroll
    for (int c = 0; c < 8; ++c) {
        const unsigned short* wp = sW + (c * 16 + lr) * 136 + lk * 8;
        short8 wf0 = *(const short8*)(wp);
        short8 wf1 = *(const short8*)(wp + 32);
        short8 wf2 = *(const short8*)(wp + 64);
        short8 wf3 = *(const short8*)(wp + 96);
        acc[c] = __builtin_amdgcn_mfma_f32_16x16x32_bf16(af0, wf0, acc[c], 0, 0, 0);
        acc[c] = __builtin_amdgcn_mfma_f32_16x16x32_bf16(af1, wf1, acc[c], 0, 0, 0);
        acc[c] = __builtin_amdgcn_mfma_f32_16x16x32_bf16(af2, wf2, acc[c], 0, 0, 0);
        acc[c] = __builtin_amdgcn_mfma_f32_16x16x32_bf16(af3, wf3, acc[c], 0, 0, 0);
    }
    const int lrow = w * 16 + lk * 4;
    #pragma unroll
    for (int c = 0; c < 8; ++c) {
        int col = c * 16 + lr;
        float b = bias1[col];
        #pragma unroll
        for (int r = 0; r < 4; ++r) {
            float v = fmaxf(acc[c][r] + b, 0.f);
            sT[(lrow + r) * 136 + col] = f2bf(v);
        }
    }
    __syncthreads();
    for (int ch = tid; ch < 2048; ch += 256) {
        int c = ch >> 4, i = ch & 15;
        *(uint4*)(sW + c * 136 + i * 8) = *(const uint4*)(Wt + 16384 + c * 128 + i * 8);
    }
    const unsigned short* tp = sT + (w * 16 + lr) * 136 + lk * 8;
    short8 bf0 = *(const short8*)(tp);
    short8 bf1 = *(const short8*)(tp + 32);
    short8 bf2_ = *(const short8*)(tp + 64);
    short8 bf3 = *(const short8*)(tp + 96);
    f32x4 acc2[8] = {};
    __syncthreads();
    #pragma unroll
    for (int c = 0; c < 8; ++c) {
        const unsigned short* wp = sW + (c * 16 + lr) * 136 + lk * 8;
        short8 wf0 = *(const short8*)(wp);
        short8 wf1 = *(const short8*)(wp + 32);
        short8 wf2 = *(const short8*)(wp + 64);
        short8 wf3 = *(const short8*)(wp + 96);
        acc2[c] = __builtin_amdgcn_mfma_f32_16x16x32_bf16(bf0, wf0, acc2[c], 0, 0, 0);
        acc2[c] = __builtin_amdgcn_mfma_f32_16x16x32_bf16(bf1, wf1, acc2[c], 0, 0, 0);
        acc2[c] = __builtin_amdgcn_mfma_f32_16x16x32_bf16(bf2_, wf2, acc2[c], 0, 0, 0);
        acc2[c] = __builtin_amdgcn_mfma_f32_16x16x32_bf16(bf3, wf3, acc2[c], 0, 0, 0);
    }
    const int drow = row0 + lk * 4;
    #pragma unroll
    for (int c = 0; c < 8; ++c) {
        int col = c * 16 + lr;
        float b = bias2[col];
        float s1 = 0.f, s2 = 0.f;
        #pragma unroll
        for (int r = 0; r < 4; ++r) {
            int grow = drow + r;
            float v = fmaxf(acc2[c][r] + b, 0.f);
            if (grow < NN) {
                yb[(size_t)grow * 128 + col] = f2bf(v);
                s1 += v;
                s2 += v * v;
            }
        }
        s1 += __shfl_xor(s1, 16); s1 += __shfl_xor(s1, 32);
        s2 += __shfl_xor(s2, 16); s2 += __shfl_xor(s2, 32);
        if (lk == 0) {
            sred[((w * 16 + lr) * 8 + c) * 2 + 0] = s1;
            sred[((w * 16 + lr) * 8 + c) * 2 + 1] = s2;
        }
    }
    __syncthreads();
    int st = tid & 1, c = (tid >> 1) & 7, lr2 = tid >> 4;
    float t = 0.f;
    #pragma unroll
    for (int w2 = 0; w2 < 4; ++w2) t += sred[((w2 * 16 + lr2) * 8 + c) * 2 + st];
    atomicAdd(&stats[st * 128 + c * 16 + lr2], t);
}

// ---------------- BN finalize ----------------
__global__ void bn_finalize_k(const float* __restrict__ stats, const float* __restrict__ gamma,
                              const float* __restrict__ beta, float* __restrict__ ss) {
    int d = threadIdx.x;
    float mu = stats[d] * (1.0f / NN);
    float var = stats[128 + d] * (1.0f / NN) - mu * mu;
    float sc = gamma[d] * rsqrtf(var + BN_EPS);
    ss[d] = sc;
    ss[128 + d] = beta[d] - mu * sc;
}

// ---------------- pool: per-graph sum of BN(y bf16) (batch sorted) -----------
__global__ __launch_bounds__(128) void pool_k(const unsigned short* __restrict__ y0,
                                              const unsigned short* __restrict__ y1,
                                              const unsigned short* __restrict__ y2,
                                              const float* __restrict__ ss,
                                              const int* __restrict__ batch, float* __restrict__ pooled) {
    int g = blockIdx.x;
    int lo = 0, hi = NN;
    while (lo < hi) { int mid = (lo + hi) >> 1; if (batch[mid] < g) lo = mid + 1; else hi = mid; }
    int s = lo;
    lo = s; hi = NN;
    while (lo < hi) { int mid = (lo + hi) >> 1; if (batch[mid] < g + 1) lo = mid + 1; else hi = mid; }
    int e = lo;
    int t = threadIdx.x;
    float sc0 = ss[t],       sh0 = ss[128 + t];
    float sc1 = ss[256 + t], sh1 = ss[384 + t];
    float sc2 = ss[512 + t], sh2 = ss[640 + t];
    float a0 = 0.f, a1 = 0.f, a2 = 0.f;
    for (int n = s; n < e; ++n) {
        a0 += fmaf(bf2f((unsigned int)y0[(size_t)n * 128 + t]), sc0, sh0);
        a1 += fmaf(bf2f((unsigned int)y1[(size_t)n * 128 + t]), sc1, sh1);
        a2 += fmaf(bf2f((unsigned int)y2[(size_t)n * 128 + t]), sc2, sh2);
    }
    pooled[(size_t)g * 384 + t] = a0;
    pooled[(size_t)g * 384 + t + 128] = a1;
    pooled[(size_t)g * 384 + t + 256] = a2;
}

// ---------------- projection head --------------------------------------------
__global__ __launch_bounds__(384) void proj_k(const float* __restrict__ pooled,
                                              const float* __restrict__ Wp1, const float* __restrict__ bp1,
                                              const float* __restrict__ Wp2, const float* __restrict__ bp2,
                                              float* __restrict__ out) {
    __shared__ float p[384];
    __shared__ float t1[384];
    int g = blockIdx.x, t = threadIdx.x;
    p[t] = pooled[(size_t)g * 384 + t];
    __syncthreads();
    float acc = bp1[t];
    #pragma unroll 4
    for (int k = 0; k < 384; ++k) acc = fmaf(p[k], Wp1[(size_t)k * 384 + t], acc);
    t1[t] = fmaxf(acc, 0.f);
    __syncthreads();
    float acc2 = bp2[t];
    #pragma unroll 4
    for (int k = 0; k < 384; ++k) acc2 = fmaf(t1[k], Wp2[(size_t)k * 384 + t], acc2);
    out[(size_t)g * 384 + t] = acc2;
}

extern "C" void kernel_launch(void* const* d_in, const int* in_sizes, int n_in,
                              void* d_out, int out_size, void* d_ws, size_t ws_size,
                              hipStream_t stream) {
    const float* x     = (const float*)d_in[0];
    const int*   ei    = (const int*)d_in[1];
    const int*   srcI  = ei;
    const int*   dstI  = ei + NE;
    const int*   batch = (const int*)d_in[2];
    const float* W1    = (const float*)d_in[3];
    const float* b1    = (const float*)d_in[4];
    const float* W2    = (const float*)d_in[5];
    const float* b2    = (const float*)d_in[6];
    const float* gamma = (const float*)d_in[7];
    const float* beta  = (const float*)d_in[8];
    const float* Wp1   = (const float*)d_in[9];
    const float* bp1   = (const float*)d_in[10];
    const float* Wp2   = (const float*)d_in[11];
    const float* bp2   = (const float*)d_in[12];
    float* out = (float*)d_out;

    float* pooled = (float*)d_ws;                     // G*384
    float* stats  = pooled + (size_t)GG * 384;        // 3*256
    float* ssbuf  = stats + 3 * 256;                  // 3*256
    int*   cnt    = (int*)(ssbuf + 3 * 256);          // N
    int*   bcur   = cnt + NN;                         // NBKT
    unsigned int* staging = (unsigned int*)(bcur + NBKT + 4);   // NBKT*BCAP
    unsigned short* ell  = (unsigned short*)(staging + (size_t)NBKT * BCAP); // N*PAD
    unsigned short* xb   = ell + (size_t)NN * PAD;             // N*128
    unsigned short* yb0  = xb + (size_t)NN * 128;
    unsigned short* yb1  = yb0 + (size_t)NN * 128;
    unsigned short* yb2  = yb1 + (size_t)NN * 128;
    unsigned short* m_bf = yb2 + (size_t)NN * 128;             // NPAD*128
    unsigned short* Wt   = m_bf + (size_t)NPAD * 128;          // 6*16384

    hipMemsetAsync(bcur, 0, NBKT * sizeof(int), stream);
    hipMemsetAsync(stats, 0, 3 * 256 * sizeof(float), stream);
    bucket_k<<<256, 256, 0, stream>>>(srcI, dstI, bcur, staging);
    xconv_k<<<1024, 256, 0, stream>>>(x, xb);
    wconv_k<<<384, 256, 0, stream>>>(W1, W2, Wt);
    ellfill_k<<<NBKT, 256, 0, stream>>>(bcur, staging, cnt, ell);

    unsigned short* ybufs[3] = {yb0, yb1, yb2};
    for (int l = 0; l < 3; ++l) {
        const unsigned short* h = (l == 0) ? xb : ybufs[l - 1];
        const float* ssl        = (l == 0) ? nullptr : (ssbuf + (l - 1) * 256);

        agg_k<<<3125, 256, 0, stream>>>(cnt, ell, h, ssl, m_bf);
        mlp_k<<<782, 256, 0, stream>>>(m_bf, Wt + (size_t)(2 * l) * 16384,
                                       b1 + l * 128, b2 + l * 128,
                                       ybufs[l], stats + l * 256);
        bn_finalize_k<<<1, 128, 0, stream>>>(stats + l * 256, gamma + l * 128, beta + l * 128, ssbuf + l * 256);
    }

    pool_k<<<GG, 128, 0, stream>>>(yb0, yb1, yb2, ssbuf, batch, pooled);
    proj_k<<<GG, 384, 0, stream>>>(pooled, Wp1, bp1, Wp2, bp2, out);
}